// Round 8
// baseline (300.316 us; speedup 1.0000x reference)
//
#include <hip/hip_runtime.h>

#define BINS  10
#define DEPTH 4          // per-wave async queue depth (chunks)
#define WPB   4          // waves per block (256 threads)
#define CHUNK 64         // float4 elems per wave-chunk (one per lane)

typedef float f4 __attribute__((ext_vector_type(4)));

typedef __attribute__((address_space(1))) void gvoid;
typedef __attribute__((address_space(3))) void lvoid;

// async DMA: 16 B/lane global -> LDS (wave-uniform base + lane*16), vmcnt-counted
__device__ __forceinline__ void async16(const f4* g, f4* l) {
    __builtin_amdgcn_global_load_lds((gvoid*)g, (lvoid*)l, 16, 0, 0);
}

#define WAITVM(N) asm volatile("s_waitcnt vmcnt(" #N ")" ::: "memory")

// Per-element update (identical arithmetic since R3; absmax == 0).
// q = t?p:(1-p) = 1-|p-t| = 1-g; bce = -log(1-g) = -ln2*log2(1-g).
// Accumulate log2(1-g); fold -ln2 in finalize. Counts via ballot->popc.
__device__ __forceinline__ void elem(float p, float t,
                                     float* __restrict__ sb,
                                     unsigned int* __restrict__ cw)
{
    float g  = fabsf(p - t);
    float l2 = __log2f(1.0f - g);
    int   bi = (int)(g * 10.0f);      // g in (0.01,0.99): bi in [0,9]
#pragma unroll
    for (int b = 0; b < BINS; ++b) {
        bool hit = (bi == b);
        unsigned long long m = __ballot(hit);
        sb[b] += hit ? l2 : 0.0f;
        cw[b] += (unsigned int)__popcll(m);
    }
}

__device__ __forceinline__ void proc4v(const f4 p, const f4 t,
                                       float* __restrict__ sb,
                                       unsigned int* __restrict__ cw)
{
    elem(p.x, t.x, sb, cw); elem(p.y, t.y, sb, cw);
    elem(p.z, t.z, sb, cw); elem(p.w, t.w, sb, cw);
}

__global__ __launch_bounds__(256) void ghm_partial(
    const f4* __restrict__ p4,
    const f4* __restrict__ t4,
    float* __restrict__ gsum,          // [BINS] floats in d_ws
    unsigned int* __restrict__ gcnt,   // [BINS] uints in d_ws
    int n4)
{
    // per-wave private double(x4)-buffered staging; NO barrier in hot loop
    __shared__ f4 lsp[WPB][DEPTH][CHUNK];
    __shared__ f4 lst[WPB][DEPTH][CHUNK];

    float        sb[BINS];
    unsigned int cw[BINS];
#pragma unroll
    for (int b = 0; b < BINS; ++b) { sb[b] = 0.0f; cw[b] = 0u; }

    const int tid  = threadIdx.x;
    const int w    = tid >> 6;
    const int lane = tid & 63;
    const int wave_global  = blockIdx.x * WPB + w;
    const int total_waves  = gridDim.x * WPB;
    const long cs  = (long)total_waves * CHUNK;     // chunk stride in f4 units
    const int  NC  = (int)(n4 / cs);                // chunks per wave (16 here)

    const f4* pg = p4 + (long)wave_global * CHUNK + lane;  // per-lane global ptr
    const f4* tg = t4 + (long)wave_global * CHUNK + lane;

#define ISSUE(k) do { int _s = (k) & (DEPTH - 1);                        \
        async16(pg + (long)(k) * cs, &lsp[w][_s][0]);                    \
        async16(tg + (long)(k) * cs, &lst[w][_s][0]); } while (0)

#define CONSUME(k) do { int _s = (k) & (DEPTH - 1);                      \
        f4 _p = lsp[w][_s][lane];                                        \
        f4 _t = lst[w][_s][lane];                                        \
        proc4v(_p, _t, sb, cw); } while (0)

    if (NC >= DEPTH) {
        ISSUE(0); ISSUE(1); ISSUE(2); ISSUE(3);
        for (int k = 0; k < NC - DEPTH; ++k) {
            WAITVM(6);          // chunk k's 2 loads drained; 3 chunks stay in flight
            CONSUME(k);
            ISSUE(k + DEPTH);   // refill the slot just consumed
        }
        WAITVM(6); CONSUME(NC - 4);
        WAITVM(4); CONSUME(NC - 3);
        WAITVM(2); CONSUME(NC - 2);
        WAITVM(0); CONSUME(NC - 1);
    } else {
        for (int k = 0; k < NC; ++k) {
            f4 p = pg[(long)k * cs];
            f4 t = tg[(long)k * cs];
            proc4v(p, t, sb, cw);
        }
    }
    // tail: f4s beyond NC*cs (empty at n4 = 2^23 with 2048x256)
    for (long j = NC * cs + blockIdx.x * blockDim.x + tid; j < n4;
         j += (long)gridDim.x * blockDim.x)
        proc4v(p4[j], t4[j], sb, cw);

#undef ISSUE
#undef CONSUME

    // -------- epilogue: wave reduce -> LDS -> one global atomic/bin/block ----
    __shared__ float        redS[BINS];
    __shared__ unsigned int redC[BINS];
    if (tid < BINS) { redS[tid] = 0.0f; redC[tid] = 0u; }
    __syncthreads();

#pragma unroll
    for (int b = 0; b < BINS; ++b) {
        float s = sb[b];
#pragma unroll
        for (int off = 32; off > 0; off >>= 1) s += __shfl_down(s, off);
        if (lane == 0) {
            atomicAdd(&redS[b], s);
            atomicAdd(&redC[b], cw[b]);   // cw is wave-uniform (ballot-derived)
        }
    }
    __syncthreads();
    if (tid < BINS) {
        atomicAdd(&gsum[tid], redS[tid]);
        atomicAdd(&gcnt[tid], redC[tid]);
    }
}

__global__ void ghm_finalize(const float* __restrict__ gsum,
                             const unsigned int* __restrict__ gcnt,
                             float* __restrict__ out)
{
    if (threadIdx.x == 0 && blockIdx.x == 0) {
        int n = 0;
#pragma unroll
        for (int b = 0; b < BINS; ++b) n += (gcnt[b] > 0u) ? 1 : 0;
        float nn = (float)(n > 0 ? n : 1);
        float acc = 0.0f;
#pragma unroll
        for (int b = 0; b < BINS; ++b) {
            if (gcnt[b] > 0u)
                acc += gsum[b] / ((float)gcnt[b] * nn);  // counts < 2^24: exact
        }
        out[0] = -0.6931471805599453f * acc;   // fold -ln(2) from log2 domain
    }
}

extern "C" void kernel_launch(void* const* d_in, const int* in_sizes, int n_in,
                              void* d_out, int out_size, void* d_ws, size_t ws_size,
                              hipStream_t stream)
{
    const float* p = (const float*)d_in[0];   // inputs (probabilities)
    const float* t = (const float*)d_in[1];   // targets (0/1 floats)
    const int n  = in_sizes[0];               // 262144*128
    const int n4 = n >> 2;                    // divisible by 4

    float*        gsum = (float*)d_ws;
    unsigned int* gcnt = (unsigned int*)((char*)d_ws + BINS * sizeof(float));

    // d_ws is re-poisoned to 0xAA before every timed launch — zero it (capturable)
    hipMemsetAsync(d_ws, 0, BINS * (sizeof(float) + sizeof(unsigned int)), stream);

    const int threads = 256;
    const int blocks  = 2048;   // 8192 waves -> NC = 16 chunks/wave at n4 = 2^23
    ghm_partial<<<blocks, threads, 0, stream>>>(
        (const f4*)p, (const f4*)t, gsum, gcnt, n4);

    ghm_finalize<<<1, 64, 0, stream>>>(gsum, gcnt, (float*)d_out);
}